// Round 17
// baseline (401.581 us; speedup 1.0000x reference)
//
#include <hip/hip_runtime.h>
#include <hip/hip_bf16.h>
#include <stdint.h>

typedef __attribute__((ext_vector_type(4))) float  f32x4;
typedef __attribute__((ext_vector_type(8))) short  s16x8;
typedef __attribute__((ext_vector_type(4))) short  s16x4;

constexpr int I_SZ = 2048;
constexpr int O_SZ = 2048;
constexpr int T_SZ = 2048;
constexpr int B_MAX = 16;

// pre-tiled layout: per (bz, tile128, ktile32): 8KB block = 8 subtiles x 1KB;
// within a subtile, byte offset l*16 holds the MFMA fragment of lane l:
// row = l&15, k = 4*(l>>4) + {0..3} and 16 + 4*(l>>4) + {0..3}
constexpr size_t XT_ELEMS = (size_t)B_MAX * T_SZ * I_SZ;
constexpr size_t WT_ELEMS = (size_t)B_MAX * I_SZ * O_SZ;
constexpr size_t WS_NEEDED = (XT_ELEMS + WT_ELEMS) * sizeof(short); // 256 MB

__device__ __forceinline__ short f2bf(float f) {
    __hip_bfloat16 h = __float2bfloat16(f);
    return *reinterpret_cast<short*>(&h);
}

__device__ __forceinline__ void gload_lds16(const void* g, void* l) {
    __builtin_amdgcn_global_load_lds(
        (const __attribute__((address_space(1))) unsigned int*)g,
        (__attribute__((address_space(3))) unsigned int*)l, 16, 0, 0);
}

// ---------------- conversion: x fp32 [B][T][I] -> pre-tiled bf16 ----------------
__global__ __launch_bounds__(256) void convA(const float* __restrict__ x,
                                             short* __restrict__ xt) {
    const int c = blockIdx.x * 256 + threadIdx.x;
    const int l  = c & 63;
    const int mi = (c >> 6) & 7;
    const int kt = (c >> 9) & 63;
    const int rest = c >> 15;
    const int mt = rest & 15, bz = rest >> 4;
    const int lr = l & 15, hi = l >> 4;
    const int m = mt * 128 + mi * 16 + lr;
    const float* src = x + ((size_t)(bz * T_SZ + m)) * I_SZ + kt * 32 + 4 * hi;
    f32x4 a = *reinterpret_cast<const f32x4*>(src);
    f32x4 b = *reinterpret_cast<const f32x4*>(src + 16);
    s16x8 h = { f2bf(a[0]), f2bf(a[1]), f2bf(a[2]), f2bf(a[3]),
                f2bf(b[0]), f2bf(b[1]), f2bf(b[2]), f2bf(b[3]) };
    *reinterpret_cast<s16x8*>(xt + (size_t)c * 8) = h;
}

__global__ __launch_bounds__(256) void convB(const float* __restrict__ fcw,
                                             const int* __restrict__ dom_id,
                                             short* __restrict__ wt) {
    const int c = blockIdx.x * 256 + threadIdx.x;
    const int l  = c & 63;
    const int ni = (c >> 6) & 7;
    const int kt = (c >> 9) & 63;
    const int rest = c >> 15;
    const int nt = rest & 15, bz = rest >> 4;
    const int lr = l & 15, hi = l >> 4;
    const int n = nt * 128 + ni * 16 + lr;
    const int dom = dom_id[bz];
    const float* src = fcw + (size_t)dom * ((size_t)I_SZ * O_SZ)
                           + (size_t)(kt * 32 + 4 * hi) * O_SZ + n;
    short h[8];
    #pragma unroll
    for (int j = 0; j < 4; ++j) {
        h[j]     = f2bf(src[(size_t)j * O_SZ]);
        h[4 + j] = f2bf(src[(size_t)(16 + j) * O_SZ]);
    }
    *reinterpret_cast<s16x8*>(wt + (size_t)c * 8) =
        *reinterpret_cast<s16x8*>(h);
}

// ---- bf16 GEMM, 128x256 tile, 4 waves, 2 blocks/CU, K128 iters, ring-2 ----
// R16 audit: 2484 cyc/K64-iter = 1242 MFMA + ~1242 per-iter sync machinery.
// This round amortizes the sync: ONE vmcnt+barrier per K128 (halved overhead).
//  - ring-2 x 32KB A-bursts (64KB LDS/block -> 128KB/CU, 2 blocks preserved).
//  - stage(T+1) issues right after the barrier -> full ~5000-cyc iter to land.
//    WAR-safe (R14 argument): it targets buf[d^1], whose readers (iter T-1)
//    completed their ds_reads before passing this barrier.
//  - iter-top ledger: outstanding <= stage(T)[8, oldest] + bq0/bq1(T)[8,
//    issued late T-1] -> vmcnt(8) retires exactly stage(T); bq prefetches
//    stay flying (compiler register-waits cover them, issued ~1200cyc ahead).
//  - bq: 2 register sets round-robin over 4 ks-phases; reload a set right
//    after consumption for phase+2 -> ~1200 cyc prefetch distance.
// Registers: af 32 + bq 32 + addr ~25 = ~110 VGPR + 128 AGPR = 238 < 256.
__global__ __launch_bounds__(256, 2) void gemm_128x256(
        const short* __restrict__ xt, const short* __restrict__ wt,
        const float* __restrict__ bw, const int* __restrict__ dom_id,
        float* __restrict__ out) {
    __shared__ short As[2][16384];   // ring-2 x 32KB (one K128 A-burst, pre-tiled)

    // bijective XCD swizzle: nwg = 2048 = 8 XCDs x 256
    const int bid = blockIdx.x;
    const int swz = (bid & 7) * 256 + (bid >> 3);
    const int bz = swz >> 7;         // 128 blocks per bz
    const int mb = (swz >> 3) & 15;  // 128-row tile index (A panel shared by 8 nb)
    const int nb = swz & 7;          // 256-col tile index

    const int t = threadIdx.x;
    const int wv = t >> 6, l = t & 63;
    const int lr = l & 15, hi = l >> 4;
    const int nti  = wv >> 1;        // which 128-col sub-tile of the 256 N-tile
    const int bsub = (wv & 1) * 4;   // which 4-subtile half within it

    // A: kt innermost in the pre-tiled layout -> a K128 burst is 32KB contiguous
    const short* Abase = xt + (size_t)(bz * 16 + mb) * 64 * 4096;
    // per-lane B fragment base (this wave's exclusive column quarter)
    const short* Bp = wt + (size_t)((bz * 16 + nb * 2 + nti) * 64) * 4096
                         + bsub * 512 + l * 8;

    auto stageA = [&](int buf, int T) {   // one K128 burst = 32KB = 8 rounds
        #pragma unroll
        for (int r = 0; r < 8; ++r)
            gload_lds16(Abase + (size_t)(4 * T) * 4096 + r * 2048 + t * 8,
                        &As[buf][r * 2048 + t * 8]);
    };

    f32x4 acc[8][4] = {};
    s16x8 bqA[4], bqB[4];            // 2 register sets, round-robin over ks

    auto loadBA = [&](int T, int ks) {   // -> set A
        const short* b = Bp + (size_t)(4 * T + ks) * 4096;
        #pragma unroll
        for (int g = 0; g < 4; ++g)
            bqA[g] = *reinterpret_cast<const s16x8*>(b + g * 512);
    };
    auto loadBB = [&](int T, int ks) {   // -> set B
        const short* b = Bp + (size_t)(4 * T + ks) * 4096;
        #pragma unroll
        for (int g = 0; g < 4; ++g)
            bqB[g] = *reinterpret_cast<const s16x8*>(b + g * 512);
    };

    auto mfma32 = [&](int d, int ks, const s16x8* bq) {
        s16x8 af[8];
        #pragma unroll
        for (int f = 0; f < 8; ++f)
            af[f] = *reinterpret_cast<const s16x8*>(
                        &As[d][ks * 4096 + f * 512 + l * 8]);
        __builtin_amdgcn_s_setprio(1);
        #pragma unroll
        for (int f = 0; f < 8; ++f)
            #pragma unroll
            for (int g = 0; g < 4; ++g)
                acc[f][g] = __builtin_amdgcn_mfma_f32_16x16x32_bf16(
                                af[f], bq[g], acc[f][g], 0, 0, 0);
        __builtin_amdgcn_s_setprio(0);
    };

    // prologue: stage(0) [8, oldest], bq ks0/ks1 of T=0 [8]
    stageA(0, 0);
    loadBA(0, 0);
    loadBB(0, 1);

    for (int T = 0; T < 16; ++T) {
        const int d = T & 1;
        const int nT = (T + 1 < 16) ? T + 1 : 15;   // tail clamp

        // retire stage(T) (oldest 8); keep bq prefetches flying
        asm volatile("s_waitcnt vmcnt(8)" ::: "memory");
        asm volatile("s_barrier" ::: "memory");      // buf[d] globally ready

        // stage(T+1): full iter (~5000 cyc) to land; WAR-safe per ring-2
        stageA(d ^ 1, nT);

        mfma32(d, 0, bqA);     // ks0 consumes set A
        loadBA(T, 2);          // set A <- ks2 (needed in ~2 phases)

        mfma32(d, 1, bqB);     // ks1 consumes set B
        loadBB(T, 3);          // set B <- ks3

        mfma32(d, 2, bqA);     // ks2
        loadBA(nT, 0);         // set A <- next iter ks0

        mfma32(d, 3, bqB);     // ks3
        loadBB(nT, 1);         // set B <- next iter ks1
    }

    asm volatile("s_waitcnt vmcnt(0)" ::: "memory");   // retire tail issues

    // epilogue: wave tile = rows mb*128..+128, cols nb*256 + wv*64 .. +64
    const int dom = dom_id[bz];
    const int col0 = nb * 256 + wv * 64;
    float bias[4];
    #pragma unroll
    for (int g = 0; g < 4; ++g)
        bias[g] = bw[dom * O_SZ + col0 + g * 16 + lr];

    const size_t obase = ((size_t)bz * T_SZ + mb * 128) * O_SZ + col0;
    #pragma unroll
    for (int f = 0; f < 8; ++f) {
        #pragma unroll
        for (int r = 0; r < 4; ++r) {
            const int row = f * 16 + hi * 4 + r;
            float* orow = out + obase + (size_t)row * O_SZ;
            #pragma unroll
            for (int g = 0; g < 4; ++g)
                orow[g * 16 + lr] = acc[f][g][r] + bias[g];
        }
    }
}

// =============== fallback (round-1 kernel) if workspace is too small ===============
constexpr int BM = 128, BN = 128, BK = 32;
constexpr int LDK = 40;
constexpr int NKT = I_SZ / BK;

__global__ __launch_bounds__(256) void dal_gemm(
    const float* __restrict__ x, const int* __restrict__ dom_id,
    const float* __restrict__ fcw, const float* __restrict__ bw,
    float* __restrict__ out)
{
    __shared__ short As[2][BM * LDK];
    __shared__ short Bs[2][BN * LDK];
    const int bz = blockIdx.z;
    const int m0 = blockIdx.y * BM, n0 = blockIdx.x * BN;
    const int dom = dom_id[bz];
    const float* Ag = x + ((size_t)bz * T_SZ + m0) * I_SZ;
    const float* Wg = fcw + (size_t)dom * ((size_t)I_SZ * O_SZ) + n0;
    const int t = threadIdx.x;
    const int am = t >> 3, ac = (t & 7) << 2;
    const int bk = (t >> 5) << 2, bn = (t & 31) << 2;
    const int wv = t >> 6, lane = t & 63;
    const int wr = (wv >> 1) << 6, wc = (wv & 1) << 6;
    const int hi = lane >> 4, lr = lane & 15;
    f32x4 acc[4][4] = {};
    f32x4 ra[4], rb[4];
    auto load_tile = [&](int kb) {
        #pragma unroll
        for (int p = 0; p < 4; ++p)
            ra[p] = *reinterpret_cast<const f32x4*>(Ag + (size_t)(am + 32 * p) * I_SZ + kb + ac);
        #pragma unroll
        for (int r = 0; r < 4; ++r)
            rb[r] = *reinterpret_cast<const f32x4*>(Wg + (size_t)(kb + bk + r) * O_SZ + bn);
    };
    auto store_tile = [&](int buf) {
        #pragma unroll
        for (int p = 0; p < 4; ++p) {
            s16x4 h = { f2bf(ra[p][0]), f2bf(ra[p][1]), f2bf(ra[p][2]), f2bf(ra[p][3]) };
            *reinterpret_cast<s16x4*>(&As[buf][(am + 32 * p) * LDK + ac]) = h;
        }
        #pragma unroll
        for (int i = 0; i < 4; ++i) {
            s16x4 h = { f2bf(rb[0][i]), f2bf(rb[1][i]), f2bf(rb[2][i]), f2bf(rb[3][i]) };
            *reinterpret_cast<s16x4*>(&Bs[buf][(bn + i) * LDK + bk]) = h;
        }
    };
    load_tile(0);
    store_tile(0);
    __syncthreads();
    for (int kt = 0; kt < NKT; ++kt) {
        const int cur = kt & 1;
        if (kt + 1 < NKT) load_tile((kt + 1) * BK);
        s16x8 af[4], bfr[4];
        #pragma unroll
        for (int im = 0; im < 4; ++im) {
            const short* p = &As[cur][(wr + im * 16 + lr) * LDK + 4 * hi];
            s16x4 lo = *reinterpret_cast<const s16x4*>(p);
            s16x4 hh = *reinterpret_cast<const s16x4*>(p + 16);
            af[im] = __builtin_shufflevector(lo, hh, 0, 1, 2, 3, 4, 5, 6, 7);
        }
        #pragma unroll
        for (int in = 0; in < 4; ++in) {
            const short* p = &Bs[cur][(wc + in * 16 + lr) * LDK + 4 * hi];
            s16x4 lo = *reinterpret_cast<const s16x4*>(p);
            s16x4 hh = *reinterpret_cast<const s16x4*>(p + 16);
            bfr[in] = __builtin_shufflevector(lo, hh, 0, 1, 2, 3, 4, 5, 6, 7);
        }
        #pragma unroll
        for (int im = 0; im < 4; ++im)
            #pragma unroll
            for (int in = 0; in < 4; ++in)
                acc[im][in] = __builtin_amdgcn_mfma_f32_16x16x32_bf16(
                                  af[im], bfr[in], acc[im][in], 0, 0, 0);
        if (kt + 1 < NKT) store_tile(cur ^ 1);
        __syncthreads();
    }
    float bias[4];
    #pragma unroll
    for (int in = 0; in < 4; ++in)
        bias[in] = bw[dom * O_SZ + n0 + wc + in * 16 + lr];
    const size_t obase = ((size_t)bz * T_SZ + m0) * O_SZ + n0;
    #pragma unroll
    for (int im = 0; im < 4; ++im) {
        #pragma unroll
        for (int r = 0; r < 4; ++r) {
            const int row = wr + im * 16 + hi * 4 + r;
            float* orow = out + obase + (size_t)row * O_SZ;
            #pragma unroll
            for (int in = 0; in < 4; ++in)
                orow[wc + in * 16 + lr] = acc[im][in][r] + bias[in];
        }
    }
}

extern "C" void kernel_launch(void* const* d_in, const int* in_sizes, int n_in,
                              void* d_out, int out_size, void* d_ws, size_t ws_size,
                              hipStream_t stream) {
    const float* x   = (const float*)d_in[0];
    const int*   dom = (const int*)d_in[1];
    const float* fcw = (const float*)d_in[2];
    const float* bw  = (const float*)d_in[3];
    float* out = (float*)d_out;
    const int B = in_sizes[1];   // 16

    if (ws_size >= WS_NEEDED && B == B_MAX) {
        short* xt = (short*)d_ws;
        short* wt = xt + XT_ELEMS;
        const int chunks = B * 16 * 64 * 512;
        convA<<<chunks / 256, 256, 0, stream>>>(x, xt);
        convB<<<chunks / 256, 256, 0, stream>>>(fcw, dom, wt);
        gemm_128x256<<<dim3(2048), dim3(256), 0, stream>>>(xt, wt, bw, dom, out);
    } else {
        dim3 grid(O_SZ / BN, T_SZ / BM, B);
        dal_gemm<<<grid, dim3(256), 0, stream>>>(x, dom, fcw, bw, out);
    }
}